// Round 17
// baseline (89.729 us; speedup 1.0000x reference)
//
#include <hip/hip_runtime.h>
#include <stdint.h>
#include <math.h>

// Multiresolution hash encoding, 16 levels.
// grids = {4,5,6,9,12,15,21,27,36,48,63,84,111,147,194,255}
// kh = 256//grid, P = floor(256/kh).
// K1 fused: blocks [0,1856)    = pooling levels 0..12, ONE WAVE PER CELL-ROW
//           (stream kh image rows as float4, col-max in regs, per-wave LDS
//            scratch, 1 sync, plain stores -> no atomics, no memset)
//           blocks [1856,2880) = levels 13..15 direct (kh=1, identity bilinear)
// K2: LDS-tiled bilinear levels 0..12 (hash+gather fused into staging),
//     16 px/thread, float4 stores, cached x-interpolated row pair.

#define NLVL 16
#define NB   16

__constant__ int   c_P[NLVL]   = {4,5,6,9,12,15,21,28,36,51,64,85,128,256,256,256};
__constant__ float c_G[NLVL]   = {4.f,5.f,6.f,9.f,12.f,15.f,21.f,27.f,36.f,48.f,63.f,84.f,111.f,147.f,194.f,255.f};
__constant__ int   c_CUM[14]   = {0,16,41,77,158,302,527,968,1752,3048,5649,9745,16970,33354};

#define CELLS_PB   33354                 // cells/batch, levels 0..12
#define CELLS_TOT  (CELLS_PB*NB)         // 533664
#define TASKS_TOT  7424                  // 464 cell-rows/batch * 16
#define POOL_BLOCKS (TASKS_TOT/4)        // 1856 (4 waves/block)
#define DIR_BLOCKS  1024
#define K1_BLOCKS   (POOL_BLOCKS + DIR_BLOCKS)   // 2880
#define TILE_BLOCKS (13*16*16)           // 3328

__device__ __forceinline__ uint32_t hash3(float m0, float m1, float m2, float g) {
    uint32_t v0 = (uint32_t)(int)(m0 * g);
    uint32_t v1 = (uint32_t)(int)(m1 * g);
    uint32_t v2 = (uint32_t)(int)(m2 * g);
    return (v0 ^ (v1 * 2654435761u) ^ (v2 * 805459861u)) & 0xFFFFu;
}

__device__ __forceinline__ float4 max4(float4 a, float4 b) {
    float4 r;
    r.x = fmaxf(a.x, b.x); r.y = fmaxf(a.y, b.y);
    r.z = fmaxf(a.z, b.z); r.w = fmaxf(a.w, b.w);
    return r;
}

// ---- K1: wave-per-cell-row pooling (levels 0..12) + direct levels 13..15 ----
__global__ __launch_bounds__(256) void pool_direct(const float* __restrict__ img,
                                                   const float* __restrict__ tab,
                                                   float* __restrict__ mws,
                                                   float* __restrict__ out)
{
    static constexpr int K_P[13]     = {4,5,6,9,12,15,21,28,36,51,64,85,128};
    static constexpr int K_KH[13]    = {64,51,42,28,21,17,12,9,7,5,4,3,2};
    static constexpr int K_CUM[13]   = {0,16,41,77,158,302,527,968,1752,3048,5649,9745,16970};
    // prefix of P (cell-rows/batch) * 16
    static constexpr int K_ROW16[13] = {0,64,144,240,384,576,816,1152,1600,2176,2992,4016,5376};

    __shared__ float4 sw[4][3][64];      // per-wave col-max scratch (12 KB)

    if (blockIdx.x >= POOL_BLOCKS) {
        // ---- direct path, levels 13..15: identity bilinear, 4 px/thread ----
        int t = (blockIdx.x - POOL_BLOCKS) * 256 + threadIdx.x;   // 262144 total
        int b = t >> 14;
        int pix0 = (t & 16383) << 2;
        const float* p = img + (size_t)b * 196608 + pix0;
        float4 i0 = *(const float4*)p;
        float4 i1 = *(const float4*)(p + 65536);
        float4 i2 = *(const float4*)(p + 131072);
#pragma unroll
        for (int lvl = 13; lvl < 16; ++lvl) {
            float g = c_G[lvl];
            const float* T = tab + (size_t)lvl * 196608;
            uint32_t g0 = hash3(i0.x, i1.x, i2.x, g);
            uint32_t g1 = hash3(i0.y, i1.y, i2.y, g);
            uint32_t g2 = hash3(i0.z, i1.z, i2.z, g);
            uint32_t g3 = hash3(i0.w, i1.w, i2.w, g);
            float3 f0 = *(const float3*)(T + g0 * 3);
            float3 f1 = *(const float3*)(T + g1 * 3);
            float3 f2 = *(const float3*)(T + g2 * 3);
            float3 f3 = *(const float3*)(T + g3 * 3);
            float4 o0, o1, o2;
            o0.x = f0.x; o1.x = f0.y; o2.x = f0.z;
            o0.y = f1.x; o1.y = f1.y; o2.y = f1.z;
            o0.z = f2.x; o1.z = f2.y; o2.z = f2.z;
            o0.w = f3.x; o1.w = f3.y; o2.w = f3.z;
            float* ob = out + ((size_t)b * 48 + 3 * lvl) * 65536 + pix0;
            *(float4*)ob            = o0;
            *(float4*)(ob + 65536)  = o1;
            *(float4*)(ob + 131072) = o2;
        }
        return;
    }

    // ---- pool path: one wave per (lvl, b, cell-row) ----
    int wid  = threadIdx.x >> 6;
    int lane = threadIdx.x & 63;
    int task = (blockIdx.x << 2) + wid;          // < 7424 exactly

    int lvl = 0;
#pragma unroll
    for (int l = 1; l < 13; ++l) lvl += (task >= K_ROW16[l]);
    int P = K_P[lvl], kh = K_KH[lvl];
    int rem = task - K_ROW16[lvl];
    int b   = rem / P;
    int cr  = rem - b * P;

    // stream kh image rows (3 channels), col-max in registers
    const float4* rp = (const float4*)(img + (size_t)b * 196608) + (size_t)(cr * kh) * 64 + lane;
    float4 cm0 = make_float4(-INFINITY, -INFINITY, -INFINITY, -INFINITY);
    float4 cm1 = cm0, cm2 = cm0;
    for (int r = 0; r < kh; ++r, rp += 64) {
        cm0 = max4(cm0, rp[0]);
        cm1 = max4(cm1, rp[16384]);
        cm2 = max4(cm2, rp[32768]);
    }
    sw[wid][0][lane] = cm0;
    sw[wid][1][lane] = cm1;
    sw[wid][2][lane] = cm2;
    __syncthreads();

    const float* f0 = (const float*)&sw[wid][0][0];
    const float* f1 = (const float*)&sw[wid][1][0];
    const float* f2 = (const float*)&sw[wid][2][0];
    for (int cx = lane; cx < P; cx += 64) {
        float m0 = -INFINITY, m1 = -INFINITY, m2 = -INFINITY;
        int cb = cx * kh;
        for (int c = cb; c < cb + kh; ++c) {
            m0 = fmaxf(m0, f0[c]);
            m1 = fmaxf(m1, f1[c]);
            m2 = fmaxf(m2, f2[c]);
        }
        int idx = K_CUM[lvl] * NB + b * P * P + cr * P + cx;
        mws[idx]                 = m0;
        mws[idx + CELLS_TOT]     = m1;
        mws[idx + 2 * CELLS_TOT] = m2;
    }
}

// ---- K2: LDS-tiled bilinear levels 0..12, cached x-interpolated row pair ----
// src = ((2o+1)*P - 256)/512 : exact int; frac exact in fp32.
__global__ __launch_bounds__(256) void render_tiles(const float* __restrict__ tab,
                                                    const float* __restrict__ mws,
                                                    float* __restrict__ out)
{
    __shared__ float4 s[34 * 34];
    int blk   = blockIdx.x;
    int tile  = blk & 15;
    int plane = blk >> 4;            // 0..207
    int lvl   = plane >> 4;
    int b     = plane & 15;
    int P     = c_P[lvl];
    int yt0   = (tile >> 2) * 64;
    int xt0   = (tile & 3) * 64;

    int nlo  = ((2 * yt0 + 1) * P - 256) >> 9;
    int r_lo = nlo < 0 ? 0 : (nlo > P - 1 ? P - 1 : nlo);
    int nhi  = (((2 * (yt0 + 63) + 1) * P - 256) >> 9) + 1;
    int r_hi = nhi < 0 ? 0 : (nhi > P - 1 ? P - 1 : nhi);
    int mlo  = ((2 * xt0 + 1) * P - 256) >> 9;
    int c_lo = mlo < 0 ? 0 : (mlo > P - 1 ? P - 1 : mlo);
    int mhi  = (((2 * (xt0 + 63) + 1) * P - 256) >> 9) + 1;
    int c_hi = mhi < 0 ? 0 : (mhi > P - 1 ? P - 1 : mhi);
    int span_y = r_hi - r_lo + 1;
    int span_x = c_hi - c_lo + 1;

    // stage: read maxima, hash, gather table feature per window cell
    int planebase = c_CUM[lvl] * NB + b * P * P;
    const float* T = tab + (size_t)lvl * 196608;
    float gmul = c_G[lvl];
    int n = span_y * span_x;
    for (int t = threadIdx.x; t < n; t += 256) {
        int r = t / span_x, c = t - r * span_x;
        int idx = planebase + (r_lo + r) * P + c_lo + c;
        float m0 = mws[idx];
        float m1 = mws[idx + CELLS_TOT];
        float m2 = mws[idx + 2 * CELLS_TOT];
        uint32_t g = hash3(m0, m1, m2, gmul);
        float3 tv = *(const float3*)(T + g * 3);
        float4 fv; fv.x = tv.x; fv.y = tv.y; fv.z = tv.z; fv.w = 0.f;
        s[t] = fv;
    }
    __syncthreads();

    int lane = threadIdx.x & 63;
    int w    = threadIdx.x >> 6;
    int xq   = lane & 15;
    int rg   = lane >> 4;
    int xb   = xt0 + xq * 4;

    int ix0t[4], ix1t[4]; float wx0t[4], wx1t[4];
#pragma unroll
    for (int j = 0; j < 4; ++j) {
        int numx = (2 * (xb + j) + 1) * P - 256;
        int ix0  = numx >> 9;
        float fx = (float)(numx & 511) * (1.0f / 512.0f);
        int ix1;
        if (ix0 < 0)           { ix0 = 0;     ix1 = 0;     fx = 0.f; }
        else if (ix0 >= P - 1) { ix0 = P - 1; ix1 = P - 1; fx = 0.f; }
        else                   { ix1 = ix0 + 1; }
        ix0t[j] = ix0 - c_lo; ix1t[j] = ix1 - c_lo; wx1t[j] = fx; wx0t[j] = 1.f - fx;
    }

    int cur0 = -1, cur1 = -1;
    float r0v[3][4], r1v[3][4];

#pragma unroll
    for (int k = 0; k < 4; ++k) {
        int y = yt0 + w * 16 + rg * 4 + k;
        int numy = (2 * y + 1) * P - 256;
        int iy0  = numy >> 9;
        float fy = (float)(numy & 511) * (1.0f / 512.0f);
        int iy1;
        if (iy0 < 0)           { iy0 = 0;     iy1 = 0;     fy = 0.f; }
        else if (iy0 >= P - 1) { iy0 = P - 1; iy1 = P - 1; fy = 0.f; }
        else                   { iy1 = iy0 + 1; }

        if (iy0 != cur0) {
            if (iy0 == cur1) {
#pragma unroll
                for (int j = 0; j < 4; ++j) {
                    r0v[0][j] = r1v[0][j]; r0v[1][j] = r1v[1][j]; r0v[2][j] = r1v[2][j];
                }
            } else {
                const float4* p0 = s + (iy0 - r_lo) * span_x;
#pragma unroll
                for (int j = 0; j < 4; ++j) {
                    float4 a = p0[ix0t[j]], q = p0[ix1t[j]];
                    r0v[0][j] = wx0t[j] * a.x + wx1t[j] * q.x;
                    r0v[1][j] = wx0t[j] * a.y + wx1t[j] * q.y;
                    r0v[2][j] = wx0t[j] * a.z + wx1t[j] * q.z;
                }
            }
            cur0 = iy0;
        }
        if (iy1 != cur1) {
            if (iy1 == cur0 && iy1 == iy0) {
#pragma unroll
                for (int j = 0; j < 4; ++j) {
                    r1v[0][j] = r0v[0][j]; r1v[1][j] = r0v[1][j]; r1v[2][j] = r0v[2][j];
                }
            } else {
                const float4* p1 = s + (iy1 - r_lo) * span_x;
#pragma unroll
                for (int j = 0; j < 4; ++j) {
                    float4 a = p1[ix0t[j]], q = p1[ix1t[j]];
                    r1v[0][j] = wx0t[j] * a.x + wx1t[j] * q.x;
                    r1v[1][j] = wx0t[j] * a.y + wx1t[j] * q.y;
                    r1v[2][j] = wx0t[j] * a.z + wx1t[j] * q.z;
                }
            }
            cur1 = iy1;
        }

        float wy1 = fy, wy0 = 1.f - fy;
        float* o = out + ((size_t)b * 48 + 3 * lvl) * 65536 + (size_t)y * 256 + xb;
#pragma unroll
        for (int c = 0; c < 3; ++c) {
            float4 q;
            q.x = wy0 * r0v[c][0] + wy1 * r1v[c][0];
            q.y = wy0 * r0v[c][1] + wy1 * r1v[c][1];
            q.z = wy0 * r0v[c][2] + wy1 * r1v[c][2];
            q.w = wy0 * r0v[c][3] + wy1 * r1v[c][3];
            *(float4*)(o + (size_t)c * 65536) = q;
        }
    }
}

extern "C" void kernel_launch(void* const* d_in, const int* in_sizes, int n_in,
                              void* d_out, int out_size, void* d_ws, size_t ws_size,
                              hipStream_t stream)
{
    const float* img = (const float*)d_in[0];   // (16,3,256,256) f32
    const float* tab = (const float*)d_in[1];   // (16,65536,3) f32
    float* out = (float*)d_out;                 // (16,48,256,256) f32
    float* mws = (float*)d_ws;                  // 1,600,992 f32 = 6.4 MB (plain stores, no init)

    hipLaunchKernelGGL(pool_direct,  dim3(K1_BLOCKS), dim3(256), 0, stream, img, tab, mws, out);
    hipLaunchKernelGGL(render_tiles, dim3(TILE_BLOCKS), dim3(256), 0, stream, tab, mws, out);
}